// Round 1
// baseline (201.260 us; speedup 1.0000x reference)
//
#include <hip/hip_runtime.h>
#include <math.h>

// Problem constants (match reference)
#define CCH 256     // channels
#define BB  512     // batch
#define NN  128     // noise samples
#define NSPLIT 4    // split of noise loop for occupancy
#define PSTRIDE 64  // packed param stride (floats) per channel

__device__ __forceinline__ float frcp(float x) { return __builtin_amdgcn_rcpf(x); }

// tanh(x) = 1 - 2/(1+exp(2x)); exact at extremes (exp->0 or inf), ~1ulp-class error
__device__ __forceinline__ float tanh_fast(float x) {
  return 1.0f - 2.0f * frcp(1.0f + __expf(2.0f * x));
}

// ---------------------------------------------------------------------------
// Precompute per-channel transformed params into packed table P[c*64 + k]:
//  [0..2]  w0 = softplus(m0)   [3..5]  b0          [6..8]  tf0 = tanh(f0)
//  [9..17] w1                  [18..20] b1         [21..23] tf1
//  [24..32] w2                 [33..35] b2         [36..38] tf2
//  [39..47] w3                 [48..50] b3         [51..53] tf3
//  [54..56] w4                 [57] b4             [58..63] pad
// ---------------------------------------------------------------------------
__global__ __launch_bounds__(256) void eb_pre(
    const float* __restrict__ m0, const float* __restrict__ b0, const float* __restrict__ f0,
    const float* __restrict__ m1, const float* __restrict__ b1, const float* __restrict__ f1,
    const float* __restrict__ m2, const float* __restrict__ b2, const float* __restrict__ f2,
    const float* __restrict__ m3, const float* __restrict__ b3, const float* __restrict__ f3,
    const float* __restrict__ m4, const float* __restrict__ b4,
    float* __restrict__ P)
{
  const int c = threadIdx.x;  // 256 threads, one per channel
  float* p = P + (size_t)c * PSTRIDE;
  auto sp = [](float x) { return (x > 20.0f) ? x : log1pf(expf(x)); };

  #pragma unroll
  for (int i = 0; i < 3; ++i) {
    p[0 + i] = sp(m0[c * 3 + i]);
    p[3 + i] = b0[c * 3 + i];
    p[6 + i] = tanhf(f0[c * 3 + i]);
  }
  #pragma unroll
  for (int i = 0; i < 9; ++i) p[9 + i] = sp(m1[c * 9 + i]);
  #pragma unroll
  for (int i = 0; i < 3; ++i) { p[18 + i] = b1[c * 3 + i]; p[21 + i] = tanhf(f1[c * 3 + i]); }
  #pragma unroll
  for (int i = 0; i < 9; ++i) p[24 + i] = sp(m2[c * 9 + i]);
  #pragma unroll
  for (int i = 0; i < 3; ++i) { p[33 + i] = b2[c * 3 + i]; p[36 + i] = tanhf(f2[c * 3 + i]); }
  #pragma unroll
  for (int i = 0; i < 9; ++i) p[39 + i] = sp(m3[c * 9 + i]);
  #pragma unroll
  for (int i = 0; i < 3; ++i) { p[48 + i] = b3[c * 3 + i]; p[51 + i] = tanhf(f3[c * 3 + i]); }
  #pragma unroll
  for (int i = 0; i < 3; ++i) p[54 + i] = sp(m4[c * 3 + i]);
  p[57] = b4[c];
  #pragma unroll
  for (int i = 58; i < 64; ++i) p[i] = 0.0f;
}

// activation: h += tf*tanh(h);  d *= 1 + tf*(1 - tanh(h_old)^2)
__device__ __forceinline__ void actf(float& h, float& d, float tf) {
  float t = tanh_fast(h);
  float u = fmaf(-t, t, 1.0f);        // 1 - t^2
  d = d * fmaf(tf, u, 1.0f);
  h = fmaf(tf, t, h);
}

// 3x3 layer: h' = W h + b ; d' = W d   (W row-major [out][in])
__device__ __forceinline__ void layer3(
    float& h0, float& h1, float& h2, float& d0, float& d1, float& d2,
    const float* __restrict__ w, const float* __restrict__ b)
{
  float n0 = fmaf(w[0], h0, fmaf(w[1], h1, fmaf(w[2], h2, b[0])));
  float n1 = fmaf(w[3], h0, fmaf(w[4], h1, fmaf(w[5], h2, b[1])));
  float n2 = fmaf(w[6], h0, fmaf(w[7], h1, fmaf(w[8], h2, b[2])));
  float e0 = fmaf(w[0], d0, fmaf(w[1], d1, w[2] * d2));
  float e1 = fmaf(w[3], d0, fmaf(w[4], d1, w[5] * d2));
  float e2 = fmaf(w[6], d0, fmaf(w[7], d1, w[8] * d2));
  h0 = n0; h1 = n1; h2 = n2; d0 = e0; d1 = e1; d2 = e2;
}

// Main: one thread per (b,c); loops over a slice of the N noise values.
// dst[s*B*C + b*C + c] = scale * sum_{n in slice} pdf(b,n,c)
__global__ __launch_bounds__(256) void eb_main(
    const float* __restrict__ inputs, const float* __restrict__ noise,
    const float* __restrict__ P, float* __restrict__ dst,
    int nper, float scale)
{
  const int bpg = (BB * CCH) / 256;              // blocks per noise-slice
  const int s   = blockIdx.x / bpg;              // noise-slice index
  const int bc  = (blockIdx.x % bpg) * 256 + threadIdx.x;
  const int c   = bc & (CCH - 1);

  // Params into registers via float4 loads
  float4 q[15];
  const float4* p4 = (const float4*)(P + (size_t)c * PSTRIDE);
  #pragma unroll
  for (int i = 0; i < 15; ++i) q[i] = p4[i];
  const float* prm = (const float*)q;

  const float x0 = inputs[bc];
  float acc = 0.0f;
  const int n0 = s * nper;

  #pragma unroll 2
  for (int n = n0; n < n0 + nper; ++n) {
    float x = x0 + noise[n * CCH + c];
    // layer 0: 1 -> 3
    float h0 = fmaf(prm[0], x, prm[3]); float d0 = prm[0];
    float h1 = fmaf(prm[1], x, prm[4]); float d1 = prm[1];
    float h2 = fmaf(prm[2], x, prm[5]); float d2 = prm[2];
    actf(h0, d0, prm[6]); actf(h1, d1, prm[7]); actf(h2, d2, prm[8]);
    // layers 1..3: 3 -> 3
    layer3(h0, h1, h2, d0, d1, d2, prm + 9,  prm + 18);
    actf(h0, d0, prm[21]); actf(h1, d1, prm[22]); actf(h2, d2, prm[23]);
    layer3(h0, h1, h2, d0, d1, d2, prm + 24, prm + 33);
    actf(h0, d0, prm[36]); actf(h1, d1, prm[37]); actf(h2, d2, prm[38]);
    layer3(h0, h1, h2, d0, d1, d2, prm + 39, prm + 48);
    actf(h0, d0, prm[51]); actf(h1, d1, prm[52]); actf(h2, d2, prm[53]);
    // layer 4: 3 -> 1, then pdf = sigmoid'(L) * dL
    float L  = fmaf(prm[54], h0, fmaf(prm[55], h1, fmaf(prm[56], h2, prm[57])));
    float dL = fmaf(prm[54], d0, fmaf(prm[55], d1, prm[56] * d2));
    float sg = frcp(1.0f + __expf(-L));
    acc = fmaf(sg * (1.0f - sg), dL, acc);
  }

  dst[s * (BB * CCH) + bc] = acc * scale;
}

__global__ __launch_bounds__(256) void eb_reduce(
    const float* __restrict__ part, float* __restrict__ out)
{
  const int i = blockIdx.x * 256 + threadIdx.x;
  float s = 0.0f;
  #pragma unroll
  for (int k = 0; k < NSPLIT; ++k) s += part[k * (BB * CCH) + i];
  out[i] = s * (1.0f / NN);
}

extern "C" void kernel_launch(void* const* d_in, const int* in_sizes, int n_in,
                              void* d_out, int out_size, void* d_ws, size_t ws_size,
                              hipStream_t stream) {
  // setup_inputs() dict order: inputs, noise, then per layer i: m_i, b_i, (f_i if i<4)
  const float* inputs = (const float*)d_in[0];
  const float* noise  = (const float*)d_in[1];
  const float* m0 = (const float*)d_in[2];
  const float* b0 = (const float*)d_in[3];
  const float* f0 = (const float*)d_in[4];
  const float* m1 = (const float*)d_in[5];
  const float* b1 = (const float*)d_in[6];
  const float* f1 = (const float*)d_in[7];
  const float* m2 = (const float*)d_in[8];
  const float* b2 = (const float*)d_in[9];
  const float* f2 = (const float*)d_in[10];
  const float* m3 = (const float*)d_in[11];
  const float* b3 = (const float*)d_in[12];
  const float* f3 = (const float*)d_in[13];
  const float* m4 = (const float*)d_in[14];
  const float* b4 = (const float*)d_in[15];
  float* out = (float*)d_out;

  float* P = (float*)d_ws;                        // 256*64*4 = 64 KiB
  const size_t pbytes = (size_t)CCH * PSTRIDE * sizeof(float);
  const size_t need   = pbytes + (size_t)NSPLIT * BB * CCH * sizeof(float);

  eb_pre<<<1, 256, 0, stream>>>(m0, b0, f0, m1, b1, f1, m2, b2, f2,
                                m3, b3, f3, m4, b4, P);

  if (ws_size >= need) {
    float* part = (float*)((char*)d_ws + pbytes);
    eb_main<<<NSPLIT * (BB * CCH / 256), 256, 0, stream>>>(
        inputs, noise, P, part, NN / NSPLIT, 1.0f);
    eb_reduce<<<BB * CCH / 256, 256, 0, stream>>>(part, out);
  } else {
    // fallback: no split, write means directly
    eb_main<<<BB * CCH / 256, 256, 0, stream>>>(
        inputs, noise, P, out, NN, 1.0f / NN);
  }
}

// Round 3
// 91.442 us; speedup vs baseline: 2.2010x; 2.2010x over previous
//
#include <hip/hip_runtime.h>
#include <math.h>

// Problem constants (match reference)
#define CCH 256     // channels
#define BB  512     // batch
#define NN  128     // noise samples

__device__ __forceinline__ float frcp(float x) { return __builtin_amdgcn_rcpf(x); }

// tanh(x) = 1 - 2/(1+exp(2x)); exact at extremes, ~ulp-class error
__device__ __forceinline__ float tanh_fast(float x) {
  return 1.0f - 2.0f * frcp(1.0f + __expf(2.0f * x));
}

// softplus(x) = log(1+exp(x)); fast native exp/log (weights ~0.2, well away from
// cancellation); guard large x where exp overflows.
__device__ __forceinline__ float sp_fast(float x) {
  return (x > 20.0f) ? x : __logf(1.0f + __expf(x));
}

// activation: h += tf*tanh(h);  d *= 1 + tf*(1 - tanh(h_old)^2)
__device__ __forceinline__ void actf(float& h, float& d, float tf) {
  float t = tanh_fast(h);
  float u = fmaf(-t, t, 1.0f);        // 1 - t^2
  d = d * fmaf(tf, u, 1.0f);
  h = fmaf(tf, t, h);
}

// 3x3 layer: h' = W h + b ; d' = W d   (W row-major [out][in])
__device__ __forceinline__ void layer3(
    float& h0, float& h1, float& h2, float& d0, float& d1, float& d2,
    const float* __restrict__ w, const float* __restrict__ bb)
{
  float n0 = fmaf(w[0], h0, fmaf(w[1], h1, fmaf(w[2], h2, bb[0])));
  float n1 = fmaf(w[3], h0, fmaf(w[4], h1, fmaf(w[5], h2, bb[1])));
  float n2 = fmaf(w[6], h0, fmaf(w[7], h1, fmaf(w[8], h2, bb[2])));
  float e0 = fmaf(w[0], d0, fmaf(w[1], d1, w[2] * d2));
  float e1 = fmaf(w[3], d0, fmaf(w[4], d1, w[5] * d2));
  float e2 = fmaf(w[6], d0, fmaf(w[7], d1, w[8] * d2));
  h0 = n0; h1 = n1; h2 = n2; d0 = e0; d1 = e1; d2 = e2;
}

// ---------------------------------------------------------------------------
// Single fused kernel: one thread per (b,c), loops over all N noise rows.
// Per-thread prologue recomputes the channel's transformed params (softplus of
// the tiny weight tower) — redundant across the 512 b-blocks but ~700 cycles,
// far cheaper than extra dispatches + a param-table roundtrip.
//
// FAST PATH (runtime data check, generic): when all factors f==0, the
// activation  logits += tanh(f)*tanh(logits)  is exactly identity and the
// derivative scale is exactly 1 — the tower collapses to L = A*x + B with
// pdf = sigmoid'(L)*A. Inner loop: 1 load + ~7 VALU (2 transcendental).
// ---------------------------------------------------------------------------
__global__ __launch_bounds__(256) void eb_fused(
    const float* __restrict__ inputs, const float* __restrict__ noise,
    const float* __restrict__ m0, const float* __restrict__ b0, const float* __restrict__ f0,
    const float* __restrict__ m1, const float* __restrict__ b1, const float* __restrict__ f1,
    const float* __restrict__ m2, const float* __restrict__ b2, const float* __restrict__ f2,
    const float* __restrict__ m3, const float* __restrict__ b3, const float* __restrict__ f3,
    const float* __restrict__ m4, const float* __restrict__ b4,
    float* __restrict__ out)
{
  const int b  = blockIdx.x;
  const int c  = threadIdx.x;
  const int bc = b * CCH + c;

  // ---- raw factor loads + zero check (decides fast path; per-lane, uniform
  // across the wave for this dataset) ----
  float F[12];
  #pragma unroll
  for (int i = 0; i < 3; ++i) {
    F[0 + i] = f0[c * 3 + i];
    F[3 + i] = f1[c * 3 + i];
    F[6 + i] = f2[c * 3 + i];
    F[9 + i] = f3[c * 3 + i];
  }
  bool zf = true;
  #pragma unroll
  for (int i = 0; i < 12; ++i) zf = zf && (F[i] == 0.0f);

  // ---- transformed weights/biases into registers ----
  float w0[3], w4[3], W1[9], W2[9], W3[9];
  float Bv0[3], Bv1[3], Bv2[3], Bv3[3];
  #pragma unroll
  for (int i = 0; i < 3; ++i) {
    w0[i]  = sp_fast(m0[c * 3 + i]);
    w4[i]  = sp_fast(m4[c * 3 + i]);
    Bv0[i] = b0[c * 3 + i];
    Bv1[i] = b1[c * 3 + i];
    Bv2[i] = b2[c * 3 + i];
    Bv3[i] = b3[c * 3 + i];
  }
  #pragma unroll
  for (int i = 0; i < 9; ++i) {
    W1[i] = sp_fast(m1[c * 9 + i]);
    W2[i] = sp_fast(m2[c * 9 + i]);
    W3[i] = sp_fast(m3[c * 9 + i]);
  }
  const float B4 = b4[c];

  const float x0 = inputs[bc];
  const float* __restrict__ nzp = noise + c;
  float acc = 0.0f;

  if (zf) {
    // ---- affine collapse: v = d/dx chain, p = bias chain ----
    float v0 = w0[0], v1 = w0[1], v2 = w0[2];
    float p0 = Bv0[0], p1 = Bv0[1], p2 = Bv0[2];
    #define APPLY(W, Bb)                                              \
      {                                                               \
        float nv0 = fmaf(W[0], v0, fmaf(W[1], v1, W[2] * v2));        \
        float nv1 = fmaf(W[3], v0, fmaf(W[4], v1, W[5] * v2));        \
        float nv2 = fmaf(W[6], v0, fmaf(W[7], v1, W[8] * v2));        \
        float np0 = fmaf(W[0], p0, fmaf(W[1], p1, fmaf(W[2], p2, Bb[0]))); \
        float np1 = fmaf(W[3], p0, fmaf(W[4], p1, fmaf(W[5], p2, Bb[1]))); \
        float np2 = fmaf(W[6], p0, fmaf(W[7], p1, fmaf(W[8], p2, Bb[2]))); \
        v0 = nv0; v1 = nv1; v2 = nv2; p0 = np0; p1 = np1; p2 = np2;   \
      }
    APPLY(W1, Bv1)
    APPLY(W2, Bv2)
    APPLY(W3, Bv3)
    #undef APPLY
    const float A  = fmaf(w4[0], v0, fmaf(w4[1], v1, w4[2] * v2));
    const float Bc = fmaf(w4[0], p0, fmaf(w4[1], p1, fmaf(w4[2], p2, B4)));
    const float L0 = fmaf(A, x0, Bc);

    // inner loop: L = A*nz + L0; acc += sigmoid'(L) = r*(1-r), r = sigmoid(L)
    #pragma unroll 8
    for (int n = 0; n < NN; ++n) {
      float L = fmaf(A, nzp[(size_t)n * CCH], L0);
      float r = frcp(1.0f + __expf(-L));
      acc += fmaf(-r, r, r);            // r - r^2 = r(1-r)
    }
    acc *= A;                           // pdf = sigma'(L) * dL/dx, dL/dx = A
  } else {
    // ---- full tower (generic path; not taken for this dataset) ----
    float tf[12];
    #pragma unroll
    for (int i = 0; i < 12; ++i) tf[i] = tanh_fast(F[i]);

    for (int n = 0; n < NN; ++n) {
      float x = x0 + nzp[(size_t)n * CCH];
      float h0 = fmaf(w0[0], x, Bv0[0]), d0 = w0[0];
      float h1 = fmaf(w0[1], x, Bv0[1]), d1 = w0[1];
      float h2 = fmaf(w0[2], x, Bv0[2]), d2 = w0[2];
      actf(h0, d0, tf[0]); actf(h1, d1, tf[1]); actf(h2, d2, tf[2]);
      layer3(h0, h1, h2, d0, d1, d2, W1, Bv1);
      actf(h0, d0, tf[3]); actf(h1, d1, tf[4]); actf(h2, d2, tf[5]);
      layer3(h0, h1, h2, d0, d1, d2, W2, Bv2);
      actf(h0, d0, tf[6]); actf(h1, d1, tf[7]); actf(h2, d2, tf[8]);
      layer3(h0, h1, h2, d0, d1, d2, W3, Bv3);
      actf(h0, d0, tf[9]); actf(h1, d1, tf[10]); actf(h2, d2, tf[11]);
      float L  = fmaf(w4[0], h0, fmaf(w4[1], h1, fmaf(w4[2], h2, B4)));
      float dL = fmaf(w4[0], d0, fmaf(w4[1], d1, w4[2] * d2));
      float sg = frcp(1.0f + __expf(-L));
      acc = fmaf(sg * (1.0f - sg), dL, acc);
    }
  }

  out[bc] = acc * (1.0f / NN);
}

extern "C" void kernel_launch(void* const* d_in, const int* in_sizes, int n_in,
                              void* d_out, int out_size, void* d_ws, size_t ws_size,
                              hipStream_t stream) {
  // setup_inputs() dict order: inputs, noise, then per layer i: m_i, b_i, (f_i if i<4)
  const float* inputs = (const float*)d_in[0];
  const float* noise  = (const float*)d_in[1];
  const float* m0 = (const float*)d_in[2];
  const float* b0 = (const float*)d_in[3];
  const float* f0 = (const float*)d_in[4];
  const float* m1 = (const float*)d_in[5];
  const float* b1 = (const float*)d_in[6];
  const float* f1 = (const float*)d_in[7];
  const float* m2 = (const float*)d_in[8];
  const float* b2 = (const float*)d_in[9];
  const float* f2 = (const float*)d_in[10];
  const float* m3 = (const float*)d_in[11];
  const float* b3 = (const float*)d_in[12];
  const float* f3 = (const float*)d_in[13];
  const float* m4 = (const float*)d_in[14];
  const float* b4 = (const float*)d_in[15];
  float* out = (float*)d_out;
  (void)d_ws; (void)ws_size; (void)in_sizes; (void)n_in; (void)out_size;

  eb_fused<<<BB, 256, 0, stream>>>(inputs, noise,
                                   m0, b0, f0, m1, b1, f1, m2, b2, f2,
                                   m3, b3, f3, m4, b4, out);
}